// Round 7
// baseline (88.349 us; speedup 1.0000x reference)
//
#include <hip/hip_runtime.h>

#define N_RAYS   65536
#define NS       256
#define NSM1     255
#define EPS_V    1e-5f
#define RPW      4   // rays per wave

typedef float f32x4 __attribute__((ext_vector_type(4)));

// DPP controls (gfx9/CDNA encodings)
#define DPP_ROW_SHR1   0x111
#define DPP_ROW_SHR2   0x112
#define DPP_ROW_SHR4   0x114
#define DPP_ROW_SHR8   0x118
#define DPP_WAVE_SHR1  0x138
#define DPP_WAVE_SHL1  0x130
#define DPP_ROW_BCAST15 0x142
#define DPP_ROW_BCAST31 0x143

template<int CTRL, int RMASK = 0xF, int BMASK = 0xF>
__device__ __forceinline__ float dpp_upd(float old_, float src) {
    return __builtin_bit_cast(float,
        __builtin_amdgcn_update_dpp(__builtin_bit_cast(int, old_),
                                    __builtin_bit_cast(int, src),
                                    CTRL, RMASK, BMASK, false));
}

// Inclusive product scan over 64 lanes (invalid/masked lanes contribute 1.0)
__device__ __forceinline__ float wave_prod_scan_incl(float p) {
    p *= dpp_upd<DPP_ROW_SHR1>(1.0f, p);
    p *= dpp_upd<DPP_ROW_SHR2>(1.0f, p);
    p *= dpp_upd<DPP_ROW_SHR4>(1.0f, p);
    p *= dpp_upd<DPP_ROW_SHR8>(1.0f, p);
    p *= dpp_upd<DPP_ROW_BCAST15, 0xA>(1.0f, p);   // rows 1,3 += lane15 of prev row
    p *= dpp_upd<DPP_ROW_BCAST31, 0xC>(1.0f, p);   // rows 2,3 += lane31
    return p;
}

// Wave sum; full total lands in lane 63 (invalid/masked lanes contribute 0.0)
__device__ __forceinline__ float wave_sum_to_lane63(float v) {
    v += dpp_upd<DPP_ROW_SHR1>(0.0f, v);
    v += dpp_upd<DPP_ROW_SHR2>(0.0f, v);
    v += dpp_upd<DPP_ROW_SHR4>(0.0f, v);
    v += dpp_upd<DPP_ROW_SHR8>(0.0f, v);
    v += dpp_upd<DPP_ROW_BCAST15, 0xA>(0.0f, v);
    v += dpp_upd<DPP_ROW_BCAST31, 0xC>(0.0f, v);
    return v;
}

__device__ __forceinline__ float fast_rcp(float x) {
    return __builtin_amdgcn_rcpf(x);
}

__device__ __forceinline__ float fast_sigmoid(float x) {
    return fast_rcp(1.0f + __builtin_amdgcn_exp2f(-x * 1.442695041f));
}

__global__ __launch_bounds__(256) void nerf_render_kernel(
    const float* __restrict__ t,
    const float* __restrict__ sdf,
    const float* __restrict__ color,
    const float* __restrict__ s_inv_log,
    float* __restrict__ out)
{
    // Wave-private staging for wi redistribution only; t_out goes straight
    // from registers (per-ray strided, L2-merged). 16 KB/block.
    __shared__ float lds_wi[4][RPW][NS];

    const int lane = threadIdx.x & 63;
    const int wv   = threadIdx.x >> 6;
    const int ray0 = blockIdx.x * (4 * RPW) + wv * RPW;

    float* __restrict__ c_out  = out;                               // 65536*3
    float* __restrict__ d_out  = out + (size_t)N_RAYS * 3;          // 65536
    float* __restrict__ wi_out = out + (size_t)N_RAYS * 4;          // 65536*255
    float* __restrict__ t_out  = wi_out + (size_t)N_RAYS * NSM1;    // 65536*255

    const float s = expf(-s_inv_log[0]);

    // ---- loads (all issued up front; 16B-aligned, fully coalesced) ----
    float4 sd[RPW], tv[RPW], c0[RPW], c1[RPW], c2[RPW];
    #pragma unroll
    for (int r = 0; r < RPW; ++r) {
        const size_t base = (size_t)(ray0 + r) * NS + (size_t)lane * 4;
        sd[r] = *reinterpret_cast<const float4*>(sdf + base);
        tv[r] = *reinterpret_cast<const float4*>(t   + base);
        const float4* cp = reinterpret_cast<const float4*>(color + base * 3);
        c0[r] = cp[0];
        c1[r] = cp[1];
        c2[r] = cp[2];
    }

    // ---- sigmoid, alpha, fused e*alpha (g), local product ----
    float g[RPW][4], Lp[RPW];
    #pragma unroll
    for (int r = 0; r < RPW; ++r) {
        float q[5];
        q[0] = fast_sigmoid(sd[r].x * s);
        q[1] = fast_sigmoid(sd[r].y * s);
        q[2] = fast_sigmoid(sd[r].z * s);
        q[3] = fast_sigmoid(sd[r].w * s);
        // next lane's q[0] (lane n <- n+1); lane 63 unused (alpha forced 0)
        q[4] = dpp_upd<DPP_WAVE_SHL1>(q[3], q[0]);

        float ecur = 1.0f;
        #pragma unroll
        for (int k = 0; k < 4; ++k) {
            float a = (q[k] - q[k + 1] + EPS_V) * fast_rcp(q[k] + EPS_V);
            a = fminf(fmaxf(a, 0.0f), 1.0f);
            if (lane == 63 && k == 3) a = 0.0f;   // sample 255 has no alpha
            g[r][k] = ecur * a;                   // e[k] * alpha[k]
            ecur *= (1.0f - a);
        }
        Lp[r] = ecur;
    }

    // ---- wave-wide exclusive product scan via DPP (pure VALU) ----
    float Ew[RPW];
    #pragma unroll
    for (int r = 0; r < RPW; ++r) {
        float p = wave_prod_scan_incl(Lp[r]);
        Ew[r] = dpp_upd<DPP_WAVE_SHR1>(1.0f, p);   // lane0 -> 1.0
    }

    // ---- wi; stage wi into LDS; t_out direct strided stores;
    //      per-lane partial sums ----
    float dsum[RPW], rs[RPW], gs[RPW], bs[RPW];
    #pragma unroll
    for (int r = 0; r < RPW; ++r) {
        float4 w4;
        w4.x = Ew[r] * g[r][0];
        w4.y = Ew[r] * g[r][1];
        w4.z = Ew[r] * g[r][2];
        w4.w = Ew[r] * g[r][3];

        *reinterpret_cast<float4*>(&lds_wi[wv][r][lane * 4]) = w4;

        // t_out: per-ray strided scalar stores from registers (L2 merges)
        const size_t wbase = (size_t)(ray0 + r) * NSM1 + (size_t)lane * 4;
        const float tvk[4] = { tv[r].x, tv[r].y, tv[r].z, tv[r].w };
        const int nw = (lane == 63) ? 3 : 4;
        #pragma unroll
        for (int k = 0; k < 4; ++k)
            if (k < nw) t_out[wbase + k] = tvk[k];

        dsum[r] = w4.x * tv[r].x + w4.y * tv[r].y + w4.z * tv[r].z + w4.w * tv[r].w;
        rs[r] = w4.x * c0[r].x + w4.y * c0[r].w + w4.z * c1[r].z + w4.w * c2[r].y;
        gs[r] = w4.x * c0[r].y + w4.y * c1[r].x + w4.z * c1[r].w + w4.w * c2[r].z;
        bs[r] = w4.x * c0[r].z + w4.y * c1[r].y + w4.z * c2[r].x + w4.w * c2[r].w;
    }

    // ---- wave reductions via DPP (16 independent VALU chains) ----
    #pragma unroll
    for (int r = 0; r < RPW; ++r) {
        dsum[r] = wave_sum_to_lane63(dsum[r]);
        rs[r]   = wave_sum_to_lane63(rs[r]);
        gs[r]   = wave_sum_to_lane63(gs[r]);
        bs[r]   = wave_sum_to_lane63(bs[r]);
    }
    if (lane == 63) {
        #pragma unroll
        for (int r = 0; r < RPW; ++r) {
            const int ray = ray0 + r;
            c_out[(size_t)ray * 3 + 0] = rs[r];
            c_out[(size_t)ray * 3 + 1] = gs[r];
            c_out[(size_t)ray * 3 + 2] = bs[r];
            d_out[ray] = dsum[r];
        }
    }

    // ---- wi flat redistribution: 255 float4 chunks per wave, full-line
    //      contiguous nt vector stores ----
    float* wdst = wi_out + (size_t)ray0 * NSM1;
    #pragma unroll
    for (int it = 0; it < 4; ++it) {
        const int idx = it * 64 + lane;      // chunk index 0..254
        if (idx < 255) {
            const int p0 = idx * 4;          // flat dword offset in wave region
            float wa[4];
            #pragma unroll
            for (int i = 0; i < 4; ++i) {
                const unsigned q  = (unsigned)(p0 + i);
                const unsigned dr = q / 255u;            // mulhi+shift
                const unsigned k  = q - dr * 255u;
                wa[i] = lds_wi[wv][dr][k];
            }
            f32x4 w4 = { wa[0], wa[1], wa[2], wa[3] };
            __builtin_nontemporal_store(w4, reinterpret_cast<f32x4*>(wdst + p0));
        }
    }
}

extern "C" void kernel_launch(void* const* d_in, const int* in_sizes, int n_in,
                              void* d_out, int out_size, void* d_ws, size_t ws_size,
                              hipStream_t stream) {
    const float* t     = (const float*)d_in[0];
    const float* sdf   = (const float*)d_in[1];
    const float* color = (const float*)d_in[2];
    const float* sil   = (const float*)d_in[3];
    float* out = (float*)d_out;

    const int blocks = N_RAYS / (4 * RPW);   // 4 waves/block, RPW rays/wave
    nerf_render_kernel<<<blocks, 256, 0, stream>>>(t, sdf, color, sil, out);
}

// Round 8
// 82.648 us; speedup vs baseline: 1.0690x; 1.0690x over previous
//
#include <hip/hip_runtime.h>

#define N_RAYS   65536
#define NS       256
#define NSM1     255
#define EPS_V    1e-5f
#define RPW      4   // rays per wave

typedef float f32x4 __attribute__((ext_vector_type(4)));

// DPP controls (gfx9/CDNA encodings)
#define DPP_ROW_SHR1    0x111
#define DPP_ROW_SHR2    0x112
#define DPP_ROW_SHR4    0x114
#define DPP_ROW_SHR8    0x118
#define DPP_WAVE_SHR1   0x138
#define DPP_WAVE_SHL1   0x130
#define DPP_ROW_BCAST15 0x142
#define DPP_ROW_BCAST31 0x143

template<int CTRL, int RMASK = 0xF, int BMASK = 0xF>
__device__ __forceinline__ float dpp_upd(float old_, float src) {
    return __builtin_bit_cast(float,
        __builtin_amdgcn_update_dpp(__builtin_bit_cast(int, old_),
                                    __builtin_bit_cast(int, src),
                                    CTRL, RMASK, BMASK, false));
}

// Inclusive product scan over 64 lanes
__device__ __forceinline__ float wave_prod_scan_incl(float p) {
    p *= dpp_upd<DPP_ROW_SHR1>(1.0f, p);
    p *= dpp_upd<DPP_ROW_SHR2>(1.0f, p);
    p *= dpp_upd<DPP_ROW_SHR4>(1.0f, p);
    p *= dpp_upd<DPP_ROW_SHR8>(1.0f, p);
    p *= dpp_upd<DPP_ROW_BCAST15, 0xA>(1.0f, p);
    p *= dpp_upd<DPP_ROW_BCAST31, 0xC>(1.0f, p);
    return p;
}

// Wave sum; full total lands in lane 63
__device__ __forceinline__ float wave_sum_to_lane63(float v) {
    v += dpp_upd<DPP_ROW_SHR1>(0.0f, v);
    v += dpp_upd<DPP_ROW_SHR2>(0.0f, v);
    v += dpp_upd<DPP_ROW_SHR4>(0.0f, v);
    v += dpp_upd<DPP_ROW_SHR8>(0.0f, v);
    v += dpp_upd<DPP_ROW_BCAST15, 0xA>(0.0f, v);
    v += dpp_upd<DPP_ROW_BCAST31, 0xC>(0.0f, v);
    return v;
}

__device__ __forceinline__ float fast_rcp(float x) {
    return __builtin_amdgcn_rcpf(x);
}

__device__ __forceinline__ float fast_sigmoid(float x) {
    return fast_rcp(1.0f + __builtin_amdgcn_exp2f(-x * 1.442695041f));
}

__global__ __launch_bounds__(256) void nerf_render_kernel(
    const float* __restrict__ t,
    const float* __restrict__ sdf,
    const float* __restrict__ color,
    const float* __restrict__ s_inv_log,
    float* __restrict__ out)
{
    // ONE wave-private staging tile, reused sequentially for wi then t.
    // Same-wave DS ops execute in order -> no barrier, WAR-safe. 16 KB/block.
    __shared__ float lds_s[4][RPW][NS];

    const int lane = threadIdx.x & 63;
    const int wv   = threadIdx.x >> 6;
    const int ray0 = blockIdx.x * (4 * RPW) + wv * RPW;

    float* __restrict__ c_out  = out;                               // 65536*3
    float* __restrict__ d_out  = out + (size_t)N_RAYS * 3;          // 65536
    float* __restrict__ wi_out = out + (size_t)N_RAYS * 4;          // 65536*255
    float* __restrict__ t_out  = wi_out + (size_t)N_RAYS * NSM1;    // 65536*255

    const float s = expf(-s_inv_log[0]);

    // ---- loads (all issued up front; 16B-aligned, fully coalesced) ----
    float4 sd[RPW], tv[RPW], c0[RPW], c1[RPW], c2[RPW];
    #pragma unroll
    for (int r = 0; r < RPW; ++r) {
        const size_t base = (size_t)(ray0 + r) * NS + (size_t)lane * 4;
        sd[r] = *reinterpret_cast<const float4*>(sdf + base);
        tv[r] = *reinterpret_cast<const float4*>(t   + base);
        const float4* cp = reinterpret_cast<const float4*>(color + base * 3);
        c0[r] = cp[0];
        c1[r] = cp[1];
        c2[r] = cp[2];
    }

    // ---- sigmoid, alpha, fused e*alpha (g), local product ----
    float g[RPW][4], Lp[RPW];
    #pragma unroll
    for (int r = 0; r < RPW; ++r) {
        float q[5];
        q[0] = fast_sigmoid(sd[r].x * s);
        q[1] = fast_sigmoid(sd[r].y * s);
        q[2] = fast_sigmoid(sd[r].z * s);
        q[3] = fast_sigmoid(sd[r].w * s);
        q[4] = dpp_upd<DPP_WAVE_SHL1>(q[3], q[0]);   // next lane's q[0]

        float ecur = 1.0f;
        #pragma unroll
        for (int k = 0; k < 4; ++k) {
            float a = (q[k] - q[k + 1] + EPS_V) * fast_rcp(q[k] + EPS_V);
            a = fminf(fmaxf(a, 0.0f), 1.0f);
            if (lane == 63 && k == 3) a = 0.0f;   // sample 255 has no alpha
            g[r][k] = ecur * a;                   // e[k] * alpha[k]
            ecur *= (1.0f - a);
        }
        Lp[r] = ecur;
    }

    // ---- wave-wide exclusive product scan via DPP (pure VALU) ----
    float Ew[RPW];
    #pragma unroll
    for (int r = 0; r < RPW; ++r) {
        float p = wave_prod_scan_incl(Lp[r]);
        Ew[r] = dpp_upd<DPP_WAVE_SHR1>(1.0f, p);   // lane0 -> 1.0
    }

    // ---- phase A: wi -> LDS; per-lane partial sums ----
    float dsum[RPW], rs[RPW], gs[RPW], bs[RPW];
    #pragma unroll
    for (int r = 0; r < RPW; ++r) {
        float4 w4;
        w4.x = Ew[r] * g[r][0];
        w4.y = Ew[r] * g[r][1];
        w4.z = Ew[r] * g[r][2];
        w4.w = Ew[r] * g[r][3];

        *reinterpret_cast<float4*>(&lds_s[wv][r][lane * 4]) = w4;

        dsum[r] = w4.x * tv[r].x + w4.y * tv[r].y + w4.z * tv[r].z + w4.w * tv[r].w;
        rs[r] = w4.x * c0[r].x + w4.y * c0[r].w + w4.z * c1[r].z + w4.w * c2[r].y;
        gs[r] = w4.x * c0[r].y + w4.y * c1[r].x + w4.z * c1[r].w + w4.w * c2[r].z;
        bs[r] = w4.x * c0[r].z + w4.y * c1[r].y + w4.z * c2[r].x + w4.w * c2[r].w;
    }

    // ---- wave reductions via DPP (16 independent VALU chains) ----
    #pragma unroll
    for (int r = 0; r < RPW; ++r) {
        dsum[r] = wave_sum_to_lane63(dsum[r]);
        rs[r]   = wave_sum_to_lane63(rs[r]);
        gs[r]   = wave_sum_to_lane63(gs[r]);
        bs[r]   = wave_sum_to_lane63(bs[r]);
    }
    if (lane == 63) {
        #pragma unroll
        for (int r = 0; r < RPW; ++r) {
            const int ray = ray0 + r;
            c_out[(size_t)ray * 3 + 0] = rs[r];
            c_out[(size_t)ray * 3 + 1] = gs[r];
            c_out[(size_t)ray * 3 + 2] = bs[r];
            d_out[ray] = dsum[r];
        }
    }

    // ---- phase A cont.: wi flat redistribution, full-line nt stores ----
    float* wdst = wi_out + (size_t)ray0 * NSM1;
    f32x4 wbuf[4];
    #pragma unroll
    for (int it = 0; it < 4; ++it) {
        const int idx = it * 64 + lane;      // chunk 0..254
        const int p0 = idx * 4;
        #pragma unroll
        for (int i = 0; i < 4; ++i) {
            const unsigned q  = (unsigned)(p0 + i);
            const unsigned dr = (idx < 255) ? (q / 255u) : 0u;
            const unsigned k  = q - dr * 255u;
            wbuf[it][i] = lds_s[wv][dr][(idx < 255) ? k : 0u];
        }
        if (idx < 255)
            __builtin_nontemporal_store(wbuf[it], reinterpret_cast<f32x4*>(wdst + p0));
    }

    // ---- phase B: t -> same LDS tile (same-wave DS ordering makes this
    //      WAR-safe vs phase A reads); redistribute; full-line nt stores ----
    #pragma unroll
    for (int r = 0; r < RPW; ++r)
        *reinterpret_cast<float4*>(&lds_s[wv][r][lane * 4]) = tv[r];

    float* tdst = t_out + (size_t)ray0 * NSM1;
    #pragma unroll
    for (int it = 0; it < 4; ++it) {
        const int idx = it * 64 + lane;
        const int p0 = idx * 4;
        f32x4 t4;
        #pragma unroll
        for (int i = 0; i < 4; ++i) {
            const unsigned q  = (unsigned)(p0 + i);
            const unsigned dr = (idx < 255) ? (q / 255u) : 0u;
            const unsigned k  = q - dr * 255u;
            t4[i] = lds_s[wv][dr][(idx < 255) ? k : 0u];
        }
        if (idx < 255)
            __builtin_nontemporal_store(t4, reinterpret_cast<f32x4*>(tdst + p0));
    }
}

extern "C" void kernel_launch(void* const* d_in, const int* in_sizes, int n_in,
                              void* d_out, int out_size, void* d_ws, size_t ws_size,
                              hipStream_t stream) {
    const float* t     = (const float*)d_in[0];
    const float* sdf   = (const float*)d_in[1];
    const float* color = (const float*)d_in[2];
    const float* sil   = (const float*)d_in[3];
    float* out = (float*)d_out;

    const int blocks = N_RAYS / (4 * RPW);   // 4 waves/block, RPW rays/wave
    nerf_render_kernel<<<blocks, 256, 0, stream>>>(t, sdf, color, sil, out);
}